// Round 8
// baseline (221.526 us; speedup 1.0000x reference)
//
#include <hip/hip_runtime.h>
#include <hip/hip_bf16.h>
#include <math.h>

// DecoderSourceTarget: out[e] = sigmoid( dot( x[src[e], 0:128], x[dst[e], 128:256] ) )
// x: (100000, 256) fp32; edge_label_index: (2, 1e6) int; out: (1e6, 1) fp32.
//
// R8: decoder is at its gather-pattern ceiling (~7.5 TB/s demand-side across
// 5 structural variants; insensitive to miss volume). Remaining gap is cvt:
// 153.6 MB at 3.9 TB/s vs 6.3 ceiling. Fix: flat-tiled cvt (no grid-stride
// loop-carried dep), 4 independent NT loads/thread, NT stores for y (R1/R6
// showed decoder speed is independent of y residency -> skipping L2
// write-allocate is free). Decoder: int2 index loads, else R7-identical.

#define HIDDEN 256
#define HALF   128

typedef _Float16 half8 __attribute__((ext_vector_type(8)));
typedef _Float16 half4 __attribute__((ext_vector_type(4)));
typedef _Float16 half2_t __attribute__((ext_vector_type(2)));
typedef float    floatx4 __attribute__((ext_vector_type(4)));
typedef float    floatx2 __attribute__((ext_vector_type(2)));

#define CVT_PER_THREAD 4

__global__ __launch_bounds__(256) void cvt_fp16_kernel(
    const float* __restrict__ x, _Float16* __restrict__ y, int n4)
{
    // Block owns a contiguous tile of 256*4 float4s; lane handles base + k*256.
    // 4 independent loads, no loop-carried dependence, per-instr coalesced.
    int base = blockIdx.x * (256 * CVT_PER_THREAD) + threadIdx.x;
    const floatx4* x4 = (const floatx4*)x;
    half4* y4 = (half4*)y;

    floatx4 v[CVT_PER_THREAD];
    int idx[CVT_PER_THREAD];
    #pragma unroll
    for (int k = 0; k < CVT_PER_THREAD; ++k) {
        idx[k] = base + k * 256;
        if (idx[k] < n4) v[k] = __builtin_nontemporal_load(x4 + idx[k]);
    }
    #pragma unroll
    for (int k = 0; k < CVT_PER_THREAD; ++k) {
        if (idx[k] < n4) {
            half4 h;
            h[0] = (_Float16)v[k][0]; h[1] = (_Float16)v[k][1];
            h[2] = (_Float16)v[k][2]; h[3] = (_Float16)v[k][3];
            __builtin_nontemporal_store(h, y4 + idx[k]);
        }
    }
}

__device__ __forceinline__ float dot8(half8 a, half8 b)
{
    float acc = 0.f;
    #pragma unroll
    for (int j = 0; j < 4; ++j) {
        half2_t aj = { a[2*j], a[2*j+1] };
        half2_t bj = { b[2*j], b[2*j+1] };
        acc = __builtin_amdgcn_fdot2(aj, bj, acc, false);
    }
    return acc;
}

__global__ __launch_bounds__(256) void decoder_fp16_kernel(
    const _Float16* __restrict__ y,
    const int* __restrict__ eidx,   // [2, n_edges] flattened
    float* __restrict__ out,
    int n_edges)
{
    int tid   = blockIdx.x * blockDim.x + threadIdx.x;
    int group = tid >> 4;       // 16 lanes per group, 2 edges per group
    int lane  = tid & 15;
    int e0 = group * 2;
    if (e0 >= n_edges) return;
    bool has2 = (e0 + 1) < n_edges;

    int s0, s1, d0, d1;
    if (has2) {
        int2 se = *(const int2*)(eidx + e0);
        int2 de = *(const int2*)(eidx + n_edges + e0);
        s0 = se.x; s1 = se.y; d0 = de.x; d1 = de.y;
    } else {
        s0 = s1 = eidx[e0];
        d0 = d1 = eidx[n_edges + e0];
    }

    // 4 independent 16B gathers — issued before any use.
    half8 a0 = ((const half8*)(y + (size_t)s0 * HIDDEN))[lane];
    half8 b0 = ((const half8*)(y + (size_t)d0 * HIDDEN + HALF))[lane];
    half8 a1 = ((const half8*)(y + (size_t)s1 * HIDDEN))[lane];
    half8 b1 = ((const half8*)(y + (size_t)d1 * HIDDEN + HALF))[lane];

    float acc0 = dot8(a0, b0);
    float acc1 = dot8(a1, b1);

    #pragma unroll
    for (int off = 8; off > 0; off >>= 1) {
        acc0 += __shfl_down(acc0, off, 16);
        acc1 += __shfl_down(acc1, off, 16);
    }

    if (lane == 0) {
        float r0 = 1.0f / (1.0f + __expf(-acc0));
        float r1 = 1.0f / (1.0f + __expf(-acc1));
        if (has2) {
            floatx2 r = { r0, r1 };
            __builtin_nontemporal_store(r, (floatx2*)out + group);  // out never re-read
        } else {
            out[e0] = r0;
        }
    }
}

// fp32 fallback in case ws_size is too small for the fp16 table.
__global__ __launch_bounds__(256) void decoder_fp32_kernel(
    const float* __restrict__ x,
    const int* __restrict__ eidx,
    float* __restrict__ out,
    int n_edges)
{
    int tid  = blockIdx.x * blockDim.x + threadIdx.x;
    int edge = tid >> 5;
    int lane = tid & 31;
    if (edge >= n_edges) return;

    int s = eidx[edge];
    int d = eidx[n_edges + edge];

    const float4* sp = (const float4*)(x + (size_t)s * HIDDEN) + lane;
    const float4* dp = (const float4*)(x + (size_t)d * HIDDEN + HALF) + lane;

    float4 a = *sp;
    float4 b = *dp;
    float acc = a.x * b.x + a.y * b.y + a.z * b.z + a.w * b.w;

    #pragma unroll
    for (int off = 16; off > 0; off >>= 1)
        acc += __shfl_down(acc, off, 32);

    if (lane == 0) {
        out[edge] = 1.0f / (1.0f + __expf(-acc));
    }
}

extern "C" void kernel_launch(void* const* d_in, const int* in_sizes, int n_in,
                              void* d_out, int out_size, void* d_ws, size_t ws_size,
                              hipStream_t stream)
{
    const float* x    = (const float*)d_in[0];
    const int*   eidx = (const int*)d_in[1];
    float*       out  = (float*)d_out;

    int n_edges = out_size;              // 1,000,000
    int n_elems = in_sizes[0];           // 25,600,000
    size_t need = (size_t)n_elems * 2;   // fp16 table bytes

    if (ws_size >= need) {
        _Float16* y = (_Float16*)d_ws;
        int n4 = n_elems / 4;

        int cvt_blocks = (n4 + 256 * CVT_PER_THREAD - 1) / (256 * CVT_PER_THREAD);
        cvt_fp16_kernel<<<cvt_blocks, 256, 0, stream>>>(x, y, n4);

        int groups = (n_edges + 1) / 2;             // 2 edges per 16-lane group
        long long total = (long long)groups * 16;
        int blocks = (int)((total + 255) / 256);
        decoder_fp16_kernel<<<blocks, 256, 0, stream>>>(y, eidx, out, n_edges);
    } else {
        int blocks = (n_edges + 7) / 8;             // 8 edges per 256-thr block
        decoder_fp32_kernel<<<blocks, 256, 0, stream>>>(x, eidx, out, n_edges);
    }
}

// Round 9
// 219.391 us; speedup vs baseline: 1.0097x; 1.0097x over previous
//
#include <hip/hip_runtime.h>
#include <hip/hip_bf16.h>
#include <math.h>

// DecoderSourceTarget: out[e] = sigmoid( dot( x[src[e], 0:128], x[dst[e], 128:256] ) )
// x: (100000, 256) fp32; edge_label_index: (2, 1e6) int; out: (1e6, 1) fp32.
//
// R9 = best-measured config of each component:
//  - cvt: NT loads of x (dead after read), NORMAL stores of y (R8 showed NT
//    y-stores cost the decoder +5.4 us in cold misses — L2 priming matters).
//  - decoder: R7 shape exactly (2 edges/16-lane group, 4 gathers in flight,
//    fdot2, NT out store). Pinned at ~7.5 TB/s demand-side gather ceiling
//    across 5 structural variants (R1/R3/R4/R5/R6).

#define HIDDEN 256
#define HALF   128

typedef _Float16 half8 __attribute__((ext_vector_type(8)));
typedef _Float16 half4 __attribute__((ext_vector_type(4)));
typedef _Float16 half2_t __attribute__((ext_vector_type(2)));
typedef float    floatx4 __attribute__((ext_vector_type(4)));
typedef float    floatx2 __attribute__((ext_vector_type(2)));

#define CVT_PER_THREAD 4

__global__ __launch_bounds__(256) void cvt_fp16_kernel(
    const float* __restrict__ x, _Float16* __restrict__ y, int n4)
{
    int base = blockIdx.x * (256 * CVT_PER_THREAD) + threadIdx.x;
    const floatx4* x4 = (const floatx4*)x;
    half4* y4 = (half4*)y;

    floatx4 v[CVT_PER_THREAD];
    int idx[CVT_PER_THREAD];
    #pragma unroll
    for (int k = 0; k < CVT_PER_THREAD; ++k) {
        idx[k] = base + k * 256;
        if (idx[k] < n4) v[k] = __builtin_nontemporal_load(x4 + idx[k]);
    }
    #pragma unroll
    for (int k = 0; k < CVT_PER_THREAD; ++k) {
        if (idx[k] < n4) {
            half4 h;
            h[0] = (_Float16)v[k][0]; h[1] = (_Float16)v[k][1];
            h[2] = (_Float16)v[k][2]; h[3] = (_Float16)v[k][3];
            y4[idx[k]] = h;    // normal store: write-allocate primes L2 for the gather
        }
    }
}

__device__ __forceinline__ float dot8(half8 a, half8 b)
{
    float acc = 0.f;
    #pragma unroll
    for (int j = 0; j < 4; ++j) {
        half2_t aj = { a[2*j], a[2*j+1] };
        half2_t bj = { b[2*j], b[2*j+1] };
        acc = __builtin_amdgcn_fdot2(aj, bj, acc, false);
    }
    return acc;
}

__global__ __launch_bounds__(256) void decoder_fp16_kernel(
    const _Float16* __restrict__ y,
    const int* __restrict__ eidx,   // [2, n_edges] flattened
    float* __restrict__ out,
    int n_edges)
{
    int tid   = blockIdx.x * blockDim.x + threadIdx.x;
    int group = tid >> 4;       // 16 lanes per group, 2 edges per group
    int lane  = tid & 15;
    int e0 = group * 2;
    if (e0 >= n_edges) return;
    bool has2 = (e0 + 1) < n_edges;
    int e1 = has2 ? (e0 + 1) : e0;

    int s0 = eidx[e0];
    int d0 = eidx[n_edges + e0];
    int s1 = eidx[e1];
    int d1 = eidx[n_edges + e1];

    // 4 independent 16B gathers — issued before any use.
    half8 a0 = ((const half8*)(y + (size_t)s0 * HIDDEN))[lane];
    half8 b0 = ((const half8*)(y + (size_t)d0 * HIDDEN + HALF))[lane];
    half8 a1 = ((const half8*)(y + (size_t)s1 * HIDDEN))[lane];
    half8 b1 = ((const half8*)(y + (size_t)d1 * HIDDEN + HALF))[lane];

    float acc0 = dot8(a0, b0);
    float acc1 = dot8(a1, b1);

    #pragma unroll
    for (int off = 8; off > 0; off >>= 1) {
        acc0 += __shfl_down(acc0, off, 16);
        acc1 += __shfl_down(acc1, off, 16);
    }

    if (lane == 0) {
        float r0 = 1.0f / (1.0f + __expf(-acc0));
        float r1 = 1.0f / (1.0f + __expf(-acc1));
        if (has2) {
            floatx2 r = { r0, r1 };
            __builtin_nontemporal_store(r, (floatx2*)out + group);  // out never re-read
        } else {
            out[e0] = r0;
        }
    }
}

// fp32 fallback in case ws_size is too small for the fp16 table.
__global__ __launch_bounds__(256) void decoder_fp32_kernel(
    const float* __restrict__ x,
    const int* __restrict__ eidx,
    float* __restrict__ out,
    int n_edges)
{
    int tid  = blockIdx.x * blockDim.x + threadIdx.x;
    int edge = tid >> 5;
    int lane = tid & 31;
    if (edge >= n_edges) return;

    int s = eidx[edge];
    int d = eidx[n_edges + edge];

    const float4* sp = (const float4*)(x + (size_t)s * HIDDEN) + lane;
    const float4* dp = (const float4*)(x + (size_t)d * HIDDEN + HALF) + lane;

    float4 a = *sp;
    float4 b = *dp;
    float acc = a.x * b.x + a.y * b.y + a.z * b.z + a.w * b.w;

    #pragma unroll
    for (int off = 16; off > 0; off >>= 1)
        acc += __shfl_down(acc, off, 32);

    if (lane == 0) {
        out[edge] = 1.0f / (1.0f + __expf(-acc));
    }
}

extern "C" void kernel_launch(void* const* d_in, const int* in_sizes, int n_in,
                              void* d_out, int out_size, void* d_ws, size_t ws_size,
                              hipStream_t stream)
{
    const float* x    = (const float*)d_in[0];
    const int*   eidx = (const int*)d_in[1];
    float*       out  = (float*)d_out;

    int n_edges = out_size;              // 1,000,000
    int n_elems = in_sizes[0];           // 25,600,000
    size_t need = (size_t)n_elems * 2;   // fp16 table bytes

    if (ws_size >= need) {
        _Float16* y = (_Float16*)d_ws;
        int n4 = n_elems / 4;

        int cvt_blocks = (n4 + 256 * CVT_PER_THREAD - 1) / (256 * CVT_PER_THREAD);
        cvt_fp16_kernel<<<cvt_blocks, 256, 0, stream>>>(x, y, n4);

        int groups = (n_edges + 1) / 2;             // 2 edges per 16-lane group
        long long total = (long long)groups * 16;
        int blocks = (int)((total + 255) / 256);
        decoder_fp16_kernel<<<blocks, 256, 0, stream>>>(y, eidx, out, n_edges);
    } else {
        int blocks = (n_edges + 7) / 8;             // 8 edges per 256-thr block
        decoder_fp32_kernel<<<blocks, 256, 0, stream>>>(x, eidx, out, n_edges);
    }
}